// Round 14
// baseline (180.431 us; speedup 1.0000x reference)
//
#include <hip/hip_runtime.h>
#include <math.h>

#define NH    114
#define WIN   130
#define WO1   66
#define WO2   37
#define C1    5
#define C2    10
#define C3    20
#define K1    65
#define K2    30
#define K3    37
#define NN    114
#define RPB   16     // rows per block = 4 waves; row-quads per wave

typedef float f32x4 __attribute__((ext_vector_type(4)));
typedef _Float16 f16x8 __attribute__((ext_vector_type(8)));

// ---- d_ws layout ----
#define WB_HALVES 24192
#define FEATS_OFF 65536

// ---- conv LDS layout (bytes), total 30976 -> 5 blocks/CU ----
//  [0,     18432): s1h  16 x 576 f16 (pos 0..65 real, 66..71 zero) | P3: scr f32 aliases at 0
//  [18432, 30976): s2h  16 x 392 f16 (P2 after inner barrier, P3)
//      time-multiplexed within s2h footprint:
//      [18432, 23552): x16h 16 x 160 f16   (P0-P1)
//      [23552, 28832): w2h  10 x 264 f16   (P0 copy .. top of P2; regs by inner barrier)
#define SMEM_BYTES 30976
#define S1H_STRIDE 576
#define W2H_STRIDE 264

__device__ __forceinline__ f32x4 splat4(float s) { f32x4 r; r.x = s; r.y = s; r.z = s; r.w = s; return r; }
__device__ __forceinline__ f32x4 pkfma4(f32x4 a, f32x4 b, f32x4 c) {
    return __builtin_elementwise_fma(a, b, c);
}
__device__ __forceinline__ float elu_f(float v) { return fmaxf(v, 0.f) + __expf(fminf(v, 0.f)) - 1.f; }
__device__ __forceinline__ f32x4 elu4(f32x4 v) {
    f32x4 r;
    r.x = elu_f(v.x); r.y = elu_f(v.y); r.z = elu_f(v.z); r.w = elu_f(v.w);
    return r;
}
__device__ __forceinline__ f32x4 rsqrt4(f32x4 v) {
    f32x4 r; r.x = rsqrtf(v.x); r.y = rsqrtf(v.y); r.z = rsqrtf(v.z); r.w = rsqrtf(v.w);
    return r;
}
__device__ __forceinline__ unsigned int pk2h(float a, float b) {
    union { _Float16 h[2]; unsigned int u; } v;
    v.h[0] = (_Float16)a; v.h[1] = (_Float16)b; return v.u;
}

// ---------------- prep kernel: format weights to f16 once ----------------
__global__ __launch_bounds__(256) void prep_kernel(
    const float* __restrict__ w1, const float* __restrict__ w2,
    const float* __restrict__ w3, _Float16* __restrict__ wb)
{
    const int gtid = blockIdx.x * 256 + threadIdx.x;
    for (int i = gtid; i < WB_HALVES; i += 32 * 256) {
        float v;
        if (i < 4224) {                     // w2h [och16][264]
            int och = i / 264, k = i - och * 264;
            int tap = k >> 3, c = k & 7;
            v = (och < 10 && c < 5 && tap < 30) ? w2[(tap * 5 + c) * 10 + och] : 0.f;
        } else if (i < 11904) {             // wph [(c,dlt)][96]
            int j = i - 4224;
            int c = j / 1536, r = j - c * 1536;
            int dlt = r / 96, u = r - dlt * 96;
            int t = u - dlt;
            v = (t >= 0 && t < K1) ? w1[t * C1 + c] : 0.f;
        } else {                            // w3t [oc32][384]
            int j = i - 11904;
            int oc = j / 384, jj = j - oc * 384;
            v = (oc < 20 && jj < 370) ? w3[jj * C3 + oc] : 0.f;
        }
        wb[i] = (_Float16)v;
    }
}

// ---------------- Kernel 1: conv pipeline ----------------
__global__ __launch_bounds__(256, 5) void conv_rows_kernel(
    const float* __restrict__ x,
    const _Float16* __restrict__ wb,
    const float* __restrict__ b1, const float* __restrict__ g1, const float* __restrict__ be1,
    const float* __restrict__ b2, const float* __restrict__ g2, const float* __restrict__ be2,
    const float* __restrict__ b3, const float* __restrict__ g3, const float* __restrict__ be3,
    float* __restrict__ feats, int nrows)
{
    __shared__ __align__(16) char smem[SMEM_BYTES];

    const int tid  = threadIdx.x;
    const int wave = tid >> 6;
    const int lane = tid & 63;

    _Float16* const s1h  = (_Float16*)smem;
    _Float16* const s2h  = (_Float16*)(smem + 18432);
    _Float16* const x16h = (_Float16*)(smem + 18432);   // P0-P1 (first 5120B of s2h region)
    _Float16* const w2h  = (_Float16*)(smem + 23552);   // P0 .. top of P2 (5280B)
    float*    const scr  = (float*)smem;                // aliases s1h (P3 only)

    const int dlt = lane & 15;
    const int grp = lane >> 4;

    // ---- P0: copy w2h global->LDS, stage x16, zero s1h tail ----
    {
        const f32x4* src = (const f32x4*)wb;
        f32x4* dst = (f32x4*)(smem + 23552);
        for (int i = tid; i < 330; i += 256) dst[i] = src[i];   // w2h 5280 B
    }
    {
        unsigned int* x16u = (unsigned int*)x16h;
        const int row0g = blockIdx.x * RPB;
        for (int q = tid; q < 16 * 80; q += 256) {
            int r = q / 80, wp = q - r * 80;
            int gr = row0g + r; if (gr >= nrows) gr = nrows - 1;
            float a = 0.f, b = 0.f;
            if (wp < 65) { const float* xp = x + (size_t)gr * WIN + 2 * wp; a = xp[0]; b = xp[1]; }
            x16u[r * 80 + wp] = pk2h(a, b);
        }
    }
    for (int i = tid; i < 16 * 24; i += 256) {   // s1h halves [528,576) per row = u32 [264,288)
        int r = i / 24, c = i - r * 24;
        ((unsigned int*)s1h)[r * 288 + 264 + c] = 0u;
    }
    __syncthreads();

    // ---- P1: conv1 toeplitz MFMA (B-frags direct from global/L1) ----
    for (int g = wave; g < 5; g += (wave == 1 ? 3 : 5)) {
        const int p0 = g * 16;
        const _Float16* xb = x16h + dlt * 160 + p0 + grp * 8;
        f16x8 a0 = *(const f16x8*)(xb);
        f16x8 a1 = *(const f16x8*)(xb + 32);
        f16x8 a2 = *(const f16x8*)(xb + 64);
        f32x4 o[C1];
        #pragma unroll
        for (int c = 0; c < C1; ++c) {
            const _Float16* wbp = wb + 4224 + (c * 16 + dlt) * 96 + grp * 8;
            f32x4 t = splat4(0.f);
            t = __builtin_amdgcn_mfma_f32_16x16x32_f16(a0, *(const f16x8*)(wbp),      t, 0, 0, 0);
            t = __builtin_amdgcn_mfma_f32_16x16x32_f16(a1, *(const f16x8*)(wbp + 32), t, 0, 0, 0);
            t = __builtin_amdgcn_mfma_f32_16x16x32_f16(a2, *(const f16x8*)(wbp + 64), t, 0, 0, 0);
            o[c] = t + splat4(b1[c]);
        }
        f32x4 m = splat4(0.f);
        #pragma unroll
        for (int c = 0; c < C1; ++c) m += o[c];
        m *= 0.2f;
        f32x4 v = splat4(0.f);
        #pragma unroll
        for (int c = 0; c < C1; ++c) { f32x4 d = o[c] - m; v = pkfma4(d, d, v); }
        f32x4 inv = rsqrt4(v * 0.2f + 1e-3f);
        f32x4 oo[C1];
        #pragma unroll
        for (int c = 0; c < C1; ++c) oo[c] = elu4((o[c] - m) * inv * g1[c] + be1[c]);
        const int p = p0 + dlt;
        if (p < WO1) {
            #pragma unroll
            for (int i = 0; i < 4; ++i) {
                const int row = grp * 4 + i;
                union { _Float16 h[8]; f16x8 v8; } pkv;
                pkv.h[0] = (_Float16)oo[0][i];
                pkv.h[1] = (_Float16)oo[1][i];
                pkv.h[2] = (_Float16)oo[2][i];
                pkv.h[3] = (_Float16)oo[3][i];
                pkv.h[4] = (_Float16)oo[4][i];
                pkv.h[5] = (_Float16)0.f;
                pkv.h[6] = (_Float16)0.f;
                pkv.h[7] = (_Float16)0.f;
                *(f16x8*)&s1h[row * S1H_STRIDE + p * 8] = pkv.v8;
            }
        }
    }
    __syncthreads();

    // ---- P2: conv2 MFMA + LN2 -> s2h (f16) ----
    {
        // B-frags (rows dlt>=10 read stale/garbage LDS; D-rows mk-masked) and A-window
        // preload BEFORE the inner barrier; s2h writes only after it.
        const _Float16* wbase = w2h + dlt * W2H_STRIDE + grp * 8;
        f16x8 wf0 = *(const f16x8*)(wbase);
        f16x8 wf1 = *(const f16x8*)(wbase + 32);
        f16x8 wf2 = *(const f16x8*)(wbase + 64);
        f16x8 wf3 = *(const f16x8*)(wbase + 96);
        f16x8 wf4 = *(const f16x8*)(wbase + 128);
        f16x8 wf5 = *(const f16x8*)(wbase + 160);
        f16x8 wf6 = *(const f16x8*)(wbase + 192);
        f16x8 wf7 = *(const f16x8*)(wbase + 224);

        float b2r[4], g2r[4], be2r[4];
        bool  mk[4];
        #pragma unroll
        for (int i = 0; i < 4; ++i) {
            int oo = grp * 4 + i;
            mk[i] = oo < 10;
            int oc = mk[i] ? oo : 9;
            b2r[i] = b2[oc]; g2r[i] = g2[oc]; be2r[i] = be2[oc];
        }
        const int r  = lane & 3;
        const int pr = (lane >> 2) & 3;
        // A-chunk c (= g+j): 8 halves at row r, offset 32c + 8*(pr+grp)
        const _Float16* arow = s1h + (4 * wave + r) * S1H_STRIDE + (pr + grp) * 8;

        f16x8 ch[17];
        #pragma unroll
        for (int c = 0; c < 8; ++c) ch[c] = *(const f16x8*)(arow + c * 32);

        __syncthreads();   // all waves done reading w2h; s2h region now writable

        unsigned int* s2u = (unsigned int*)s2h;
        if (lane < 44) {
            int r4 = lane / 11, jj = lane - r4 * 11;
            s2u[(4 * wave + r4) * 196 + 185 + jj] = 0u;
        }

        #pragma unroll
        for (int g = 0; g < 10; ++g) {
            if (g + 8 <= 16) ch[g + 8] = *(const f16x8*)(arow + (g + 8) * 32);

            f32x4 aA = splat4(0.f), aB = splat4(0.f);
            aA = __builtin_amdgcn_mfma_f32_16x16x32_f16(wf0, ch[g + 0], aA, 0, 0, 0);
            aB = __builtin_amdgcn_mfma_f32_16x16x32_f16(wf1, ch[g + 1], aB, 0, 0, 0);
            aA = __builtin_amdgcn_mfma_f32_16x16x32_f16(wf2, ch[g + 2], aA, 0, 0, 0);
            aB = __builtin_amdgcn_mfma_f32_16x16x32_f16(wf3, ch[g + 3], aB, 0, 0, 0);
            aA = __builtin_amdgcn_mfma_f32_16x16x32_f16(wf4, ch[g + 4], aA, 0, 0, 0);
            aB = __builtin_amdgcn_mfma_f32_16x16x32_f16(wf5, ch[g + 5], aB, 0, 0, 0);
            aA = __builtin_amdgcn_mfma_f32_16x16x32_f16(wf6, ch[g + 6], aA, 0, 0, 0);
            aB = __builtin_amdgcn_mfma_f32_16x16x32_f16(wf7, ch[g + 7], aB, 0, 0, 0);
            f32x4 acc = aA + aB;

            float v0 = acc.x + b2r[0], v1 = acc.y + b2r[1];
            float v2 = acc.z + b2r[2], v3 = acc.w + b2r[3];
            float sp = (mk[0] ? v0 : 0.f) + (mk[1] ? v1 : 0.f)
                     + (mk[2] ? v2 : 0.f) + (mk[3] ? v3 : 0.f);
            sp += __shfl_xor(sp, 16);
            sp += __shfl_xor(sp, 32);
            const float mean = sp * 0.1f;
            float d0 = v0 - mean, d1 = v1 - mean, d2 = v2 - mean, d3 = v3 - mean;
            float sq = (mk[0] ? d0 * d0 : 0.f) + (mk[1] ? d1 * d1 : 0.f)
                     + (mk[2] ? d2 * d2 : 0.f) + (mk[3] ? d3 * d3 : 0.f);
            sq += __shfl_xor(sq, 16);
            sq += __shfl_xor(sq, 32);
            const float inv = rsqrtf(sq * 0.1f + 1e-3f);

            const int p = g * 4 + pr;
            if (p < WO2) {
                float e0 = elu_f(d0 * inv * g2r[0] + be2r[0]);
                float e1 = elu_f(d1 * inv * g2r[1] + be2r[1]);
                float e2 = elu_f(d2 * inv * g2r[2] + be2r[2]);
                float e3 = elu_f(d3 * inv * g2r[3] + be2r[3]);
                int base = (4 * wave + r) * 196 + p * 5 + grp * 2;
                if (mk[0]) s2u[base]     = pk2h(e0, e1);
                if (mk[2]) s2u[base + 1] = pk2h(e2, e3);
            }
        }
    }
    __syncthreads();

    // ---- P3: conv3 MFMA + LN3 -> feats (scr aliases dead s1h) ----
    {
        const int tile  = wave & 1;
        const int khalf = wave >> 1;
        const int col   = lane & 15;

        const _Float16* arow = s2h + col * 392 + (lane >> 4) * 8;
        const _Float16* brow = wb + 11904 + (size_t)(tile * 16 + col) * 384 + (lane >> 4) * 8;

        f32x4 acc = splat4(0.f);
        #pragma unroll
        for (int s = 0; s < 6; ++s) {
            const int st = khalf * 6 + s;
            f16x8 af = *(const f16x8*)(arow + st * 32);
            f16x8 bf = *(const f16x8*)(brow + st * 32);
            acc = __builtin_amdgcn_mfma_f32_16x16x32_f16(af, bf, acc, 0, 0, 0);
        }
        f32x4* scrv = (f32x4*)scr;
        if (khalf == 1) scrv[tile * 64 + lane] = acc;
        __syncthreads();

        const int ocg = tile * 16 + col;
        const bool vc = ocg < 20;
        const int occ = vc ? ocg : 19;
        f32x4 vv = splat4(0.f);
        float* sums = scr + 512;
        if (khalf == 0) {
            acc += scrv[tile * 64 + lane];
            vv = acc + splat4(b3[occ]);
            if (!vc) vv = splat4(0.f);
            f32x4 s = vv, q = vv * vv;
            #pragma unroll
            for (int d = 1; d < 16; d <<= 1) {
                s.x += __shfl_xor(s.x, d); s.y += __shfl_xor(s.y, d);
                s.z += __shfl_xor(s.z, d); s.w += __shfl_xor(s.w, d);
                q.x += __shfl_xor(q.x, d); q.y += __shfl_xor(q.y, d);
                q.z += __shfl_xor(q.z, d); q.w += __shfl_xor(q.w, d);
            }
            if (col == 0) {
                const int rb = (lane >> 4) * 4;
                #pragma unroll
                for (int i = 0; i < 4; ++i) {
                    sums[tile * 64 + rb + i]      = s[i];
                    sums[tile * 64 + 16 + rb + i] = q[i];
                }
            }
        }
        __syncthreads();
        if (khalf == 0) {
            const float gg = g3[occ], bb = be3[occ];
            #pragma unroll
            for (int i = 0; i < 4; ++i) {
                const int row = (lane >> 4) * 4 + i;
                const float ts = sums[row] + sums[64 + row];
                const float tq = sums[16 + row] + sums[80 + row];
                const float mn = ts * 0.05f;
                const float vr = tq * 0.05f - mn * mn;
                const float iv = rsqrtf(vr + 1e-3f);
                if (vc) {
                    const int grow = blockIdx.x * RPB + row;
                    if (grow < nrows)
                        feats[(size_t)grow * C3 + ocg] = elu_f((vv[i] - mn) * iv * gg + bb);
                }
            }
        }
    }
}

// ---------------- Kernel 2: per-batch graph block, MFMA + symmetric corr ----------------
__global__ __launch_bounds__(256) void graph_kernel(
    const float* __restrict__ feats,
    const float* __restrict__ agent_w, const float* __restrict__ agent_b,
    const float* __restrict__ g1w, const float* __restrict__ g1b,
    const float* __restrict__ g2w, const float* __restrict__ g2b,
    const float* __restrict__ dw, const float* __restrict__ db,
    const int* __restrict__ rlp,
    float* __restrict__ out)
{
    __shared__ __align__(16) char gsm[61104];
    _Float16* const sLh  = (_Float16*)(gsm);
    _Float16* const sfcH = (_Float16*)(gsm + 34816);
    float*    const h2T  = (float*)(gsm + 34816);
    float*    const sfe  = (float*)(gsm + 45056);
    float*    const h1f  = (float*)(gsm + 45056);
    _Float16* const t1h  = (_Float16*)(gsm + 54176);
    float* const snrm  = (float*)(gsm + 58528);
    float* const sidx  = (float*)(gsm + 58984);
    float* const sdv   = (float*)(gsm + 59440);
    float* const red   = (float*)(gsm + 59896);
    float* const sfeat = (float*)(gsm + 59912);
    float* const sg1   = (float*)(gsm + 59952);
    float* const sg1b  = sg1 + 200;
    float* const sg2   = sg1b + 10;
    float* const sg2b  = sg2 + 50;
    float* const sdw   = sg2b + 5;
    float* const sdb   = sdw + 20;

    const int tid  = threadIdx.x;
    const int wave = tid >> 6;
    const int lane = tid & 63;
    const int b = blockIdx.x;
    const float* F = feats + (size_t)b * (NN * C3);
    const int rl = rlp[0];
    const float aw_b = agent_b[0];

    // ---- P0 ----
    {
        f32x4* z = (f32x4*)gsm;
        for (int i = tid; i < 2816; i += 256) z[i] = splat4(0.f);
        f32x4* z2 = (f32x4*)(gsm + 54176);
        if (tid < 272) z2[tid] = splat4(0.f);
        if (tid < 200) sg1[tid] = g1w[tid];
        if (tid < 10)  sg1b[tid] = g1b[tid];
        if (tid < 50)  sg2[tid] = g2w[tid];
        if (tid < 5)   sg2b[tid] = g2b[tid];
        if (tid < 20)  sdw[tid] = dw[tid];
        if (tid < 2)   sdb[tid] = db[tid];
    }
    __syncthreads();

    // ---- P1 ----
    for (int n = tid; n < NN; n += 256) {
        float f[C3];
        float m = 0.f;
        #pragma unroll
        for (int d = 0; d < C3; ++d) { f[d] = F[n * C3 + d]; m += f[d]; }
        m *= (1.f / C3);
        float nr = 0.f, ag = 0.f;
        unsigned int* dst = (unsigned int*)(sfcH + n * 40);
        #pragma unroll
        for (int d = 0; d < C3; d += 2) {
            sfe[n * C3 + d]     = f[d];
            sfe[n * C3 + d + 1] = f[d + 1];
            float c0 = f[d] - m, c1 = f[d + 1] - m;
            dst[d >> 1] = pk2h(c0, c1);
            nr = fmaf(c0, c0, fmaf(c1, c1, nr));
            ag = fmaf(f[d], agent_w[d], fmaf(f[d + 1], agent_w[d + 1], ag));
        }
        snrm[n] = sqrtf(nr);
        sidx[n] = rl ? (1.f / (1.f + __expf(-(ag + aw_b)))) : 1.f;
    }
    __syncthreads();

    // ---- P2: corr via MFMA, upper-triangular tiles (36), mirror stores ----
    {
        float psum = 0.f;
        const int row = lane & 15;
        const int kg  = lane >> 4;
        for (int tt = 0; tt < 9; ++tt) {
            int idx = wave * 9 + tt;            // 0..35 over 4 waves
            int tr = 0, rem = idx;
            while (rem >= 8 - tr) { rem -= 8 - tr; ++tr; }
            const int tc = tr + rem;
            f16x8 a  = *(const f16x8*)(sfcH + (tr * 16 + row) * 40 + kg * 8);
            f16x8 bf = *(const f16x8*)(sfcH + (tc * 16 + row) * 40 + kg * 8);
            f32x4 acc = __builtin_amdgcn_mfma_f32_16x16x32_f16(a, bf, splat4(0.f), 0, 0, 0);
            const int c = tc * 16 + row;
            const float nc = (c < NN) ? snrm[c] : 1.f;
            const float wgt = (tr == tc) ? 1.f : 2.f;
            const bool mirror = (tr != tc);
            #pragma unroll
            for (int i = 0; i < 4; ++i) {
                const int r = tr * 16 + kg * 4 + i;
                float dist = 0.f;
                if (r < NN && c < NN && r != c)
                    dist = 1.f - acc[i] * __frcp_rn(snrm[r] * nc);
                psum += wgt * dist;
                sLh[r * 136 + c] = (_Float16)dist;
                if (mirror) sLh[c * 136 + r] = (_Float16)dist;
            }
        }
        #pragma unroll
        for (int d = 1; d < 64; d <<= 1) psum += __shfl_xor(psum, d);
        if (lane == 0) red[wave] = psum;
    }
    __syncthreads();

    // ---- P3 ----
    {
        const float sg = (red[0] + red[1] + red[2] + red[3]) * (1.f / (float)(NN * NN));
        const float inv2s2 = 1.f / (2.f * sg * sg);
        if (tid < 228) {
            const int r = tid >> 1, half = tid & 1;
            const float idxr = sidx[r];
            float rsum = 0.f;
            _Float16* rp = sLh + r * 136 + half * 57;
            const int c0 = half * 57;
            for (int j = 0; j < 57; ++j) {
                float d = (float)rp[j];
                float A = idxr * sidx[c0 + j] * __expf(-d * d * inv2s2);
                rsum += A;
                rp[j] = (_Float16)A;
            }
            rsum += __shfl_xor(rsum, 1);
            if (half == 0) {
                float dv = rsqrtf(rsum);
                if (isinf(dv)) dv = 0.f;
                sdv[r] = dv;
            }
        }
    }
    __syncthreads();

    // ---- P4 ----
    {
        unsigned int* L32 = (unsigned int*)sLh;
        for (int e2 = tid; e2 < NN * 57; e2 += 256) {
            const int r = e2 / 57, cp = e2 - r * 57;
            const unsigned int u = L32[r * 68 + cp];
            union { unsigned int uu; _Float16 h[2]; } in;
            in.uu = u;
            const float dr = sdv[r];
            float v0 = (float)in.h[0] * dr * sdv[2 * cp];
            float v1 = (float)in.h[1] * dr * sdv[2 * cp + 1];
            L32[r * 68 + cp] = pk2h(v0, v1);
        }
        for (int e = tid; e < NN * C2; e += 256) {
            const int n = e / C2, o = e - n * C2;
            float acc = 0.f;
            #pragma unroll
            for (int d = 0; d < C3; ++d) acc = fmaf(sfe[n * C3 + d], sg1[d * C2 + o], acc);
            t1h[o * 136 + n] = (_Float16)(acc * sidx[n] + sg1b[o]);
        }
    }
    __syncthreads();

    // ---- P5 ----
    {
        const int row = lane & 15;
        const int kg  = lane >> 4;
        #pragma unroll
        for (int tt = 0; tt < 2; ++tt) {
            const int tr = wave * 2 + tt;
            f32x4 acc = splat4(0.f);
            #pragma unroll
            for (int ks = 0; ks < 4; ++ks) {
                f16x8 a = *(const f16x8*)(sLh + (tr * 16 + row) * 136 + ks * 32 + kg * 8);
                f16x8 bf = *(const f16x8*)(t1h + row * 136 + ks * 32 + kg * 8);
                acc = __builtin_amdgcn_mfma_f32_16x16x32_f16(a, bf, acc, 0, 0, 0);
            }
            #pragma unroll
            for (int i = 0; i < 4; ++i) {
                const int n = tr * 16 + kg * 4 + i;
                h1f[n * 16 + row] = elu_f(acc[i]);
            }
        }
    }
    __syncthreads();

    // ---- P6 ----
    for (int e = tid; e < NN * C1; e += 256) {
        const int n = e / C1, c = e - n * C1;
        float acc = sg2b[c];
        #pragma unroll
        for (int o = 0; o < C2; ++o) acc = fmaf(h1f[n * 16 + o], sg2[o * C1 + c], acc);
        t1h[c * 136 + n] = (_Float16)acc;
    }
    __syncthreads();

    // ---- P7 ----
    {
        const int row = lane & 15;
        const int kg  = lane >> 4;
        #pragma unroll
        for (int tt = 0; tt < 2; ++tt) {
            const int tr = wave * 2 + tt;
            f32x4 acc = splat4(0.f);
            #pragma unroll
            for (int ks = 0; ks < 4; ++ks) {
                f16x8 a = *(const f16x8*)(sLh + (tr * 16 + row) * 136 + ks * 32 + kg * 8);
                f16x8 bf = *(const f16x8*)(t1h + row * 136 + ks * 32 + kg * 8);
                acc = __builtin_amdgcn_mfma_f32_16x16x32_f16(a, bf, acc, 0, 0, 0);
            }
            if (row < C1) {
                #pragma unroll
                for (int i = 0; i < 4; ++i) {
                    const int n = tr * 16 + kg * 4 + i;
                    h2T[row * 132 + n] = elu_f(acc[i]);
                }
            }
        }
    }
    __syncthreads();

    // ---- P8 ----
    if (tid < 160) {
        const int c = tid >> 5, s = tid & 31;
        float pmax = -INFINITY, rmin = INFINITY, sum = 0.f;
        #pragma unroll
        for (int k = 0; k < 4; ++k) {
            const int n = s + 32 * k;
            if (n < NN) {
                float v = h2T[c * 132 + n];
                pmax = fmaxf(pmax, v);
                rmin = fminf(rmin, 1.f / v);
                sum += v;
            }
        }
        #pragma unroll
        for (int d = 16; d > 0; d >>= 1) {
            pmax = fmaxf(pmax, __shfl_xor(pmax, d));
            rmin = fminf(rmin, __shfl_xor(rmin, d));
            sum += __shfl_xor(sum, d);
        }
        if (s == 0) {
            float nmax = 1.f / rmin;
            sfeat[c] = (pmax == 0.f) ? nmax : pmax;
            sfeat[C1 + c] = sum;
        }
    }
    __syncthreads();

    if (tid == 0) {
        float l0 = sdb[0], l1 = sdb[1];
        #pragma unroll
        for (int j = 0; j < 10; ++j) {
            l0 += sfeat[j] * sdw[j * 2 + 0];
            l1 += sfeat[j] * sdw[j * 2 + 1];
        }
        float mx = fmaxf(l0, l1);
        float e0 = expf(l0 - mx), e1 = expf(l1 - mx);
        float s = e0 + e1;
        out[b * 2 + 0] = e0 / s;
        out[b * 2 + 1] = e1 / s;
    }
}

extern "C" void kernel_launch(void* const* d_in, const int* in_sizes, int n_in,
                              void* d_out, int out_size, void* d_ws, size_t ws_size,
                              hipStream_t stream) {
    const float* x       = (const float*)d_in[0];
    const float* conv1_w = (const float*)d_in[1];
    const float* conv1_b = (const float*)d_in[2];
    const float* ln1_g   = (const float*)d_in[3];
    const float* ln1_b   = (const float*)d_in[4];
    const float* conv2_w = (const float*)d_in[5];
    const float* conv2_b = (const float*)d_in[6];
    const float* ln2_g   = (const float*)d_in[7];
    const float* ln2_b   = (const float*)d_in[8];
    const float* conv3_w = (const float*)d_in[9];
    const float* conv3_b = (const float*)d_in[10];
    const float* ln3_g   = (const float*)d_in[11];
    const float* ln3_b   = (const float*)d_in[12];
    const float* agent_w = (const float*)d_in[13];
    const float* agent_b = (const float*)d_in[14];
    const float* gconv1_w= (const float*)d_in[15];
    const float* gconv1_b= (const float*)d_in[16];
    const float* gconv2_w= (const float*)d_in[17];
    const float* gconv2_b= (const float*)d_in[18];
    const float* dense_w = (const float*)d_in[19];
    const float* dense_b = (const float*)d_in[20];
    const int*   rl      = (const int*)d_in[21];
    float* out = (float*)d_out;

    const int B = in_sizes[0] / (NH * WIN);
    const int nrows = B * NH;
    _Float16* wbuf = (_Float16*)d_ws;
    float* feats = (float*)((char*)d_ws + FEATS_OFF);

    dim3 block(256);
    hipLaunchKernelGGL(prep_kernel, dim3(32), block, 0, stream,
                       conv1_w, conv2_w, conv3_w, wbuf);

    dim3 grid1((nrows + RPB - 1) / RPB);
    hipLaunchKernelGGL(conv_rows_kernel, grid1, block, 0, stream,
                       x, (const _Float16*)wbuf,
                       conv1_b, ln1_g, ln1_b,
                       conv2_b, ln2_g, ln2_b,
                       conv3_b, ln3_g, ln3_b,
                       feats, nrows);

    dim3 grid2(B);
    hipLaunchKernelGGL(graph_kernel, grid2, block, 0, stream,
                       feats, agent_w, agent_b,
                       gconv1_w, gconv1_b, gconv2_w, gconv2_b,
                       dense_w, dense_b, rl, out);
}

// Round 15
// 164.428 us; speedup vs baseline: 1.0973x; 1.0973x over previous
//
#include <hip/hip_runtime.h>
#include <math.h>

#define NH    114
#define WIN   130
#define WO1   66
#define WO2   37
#define C1    5
#define C2    10
#define C3    20
#define K1    65
#define K2    30
#define K3    37
#define NN    114
#define RPB   16     // rows per block = 4 waves; row-quads per wave

typedef float f32x4 __attribute__((ext_vector_type(4)));
typedef _Float16 f16x8 __attribute__((ext_vector_type(8)));

// ---- d_ws layout ----
#define WB_HALVES 24192
#define FEATS_OFF 65536

// ---- conv LDS layout (bytes), total 30976 -> 5 blocks/CU (LDS-limited; VGPR=64 allows 8) ----
//  [0,     18432): s1h  16 x 576 f16 (pos 0..65 real, 66..71 zero) | P3: scr f32 aliases at 0
//  [18432, 30976): s2h  16 x 392 f16 (P2 after inner barrier, P3)
//      time-multiplexed within s2h footprint:
//      [18432, 23552): x16h 16 x 160 f16   (P0-P1)
//      [23552, 28832): w2h  10 x 264 f16   (P0 copy .. top of P2; regs by inner barrier)
#define SMEM_BYTES 30976
#define S1H_STRIDE 576
#define W2H_STRIDE 264

__device__ __forceinline__ f32x4 splat4(float s) { f32x4 r; r.x = s; r.y = s; r.z = s; r.w = s; return r; }
__device__ __forceinline__ f32x4 pkfma4(f32x4 a, f32x4 b, f32x4 c) {
    return __builtin_elementwise_fma(a, b, c);
}
__device__ __forceinline__ float elu_f(float v) { return fmaxf(v, 0.f) + __expf(fminf(v, 0.f)) - 1.f; }
__device__ __forceinline__ f32x4 elu4(f32x4 v) {
    f32x4 r;
    r.x = elu_f(v.x); r.y = elu_f(v.y); r.z = elu_f(v.z); r.w = elu_f(v.w);
    return r;
}
__device__ __forceinline__ f32x4 rsqrt4(f32x4 v) {
    f32x4 r; r.x = rsqrtf(v.x); r.y = rsqrtf(v.y); r.z = rsqrtf(v.z); r.w = rsqrtf(v.w);
    return r;
}
__device__ __forceinline__ unsigned int pk2h(float a, float b) {
    union { _Float16 h[2]; unsigned int u; } v;
    v.h[0] = (_Float16)a; v.h[1] = (_Float16)b; return v.u;
}

// ---------------- prep kernel: format weights to f16 once ----------------
__global__ __launch_bounds__(256) void prep_kernel(
    const float* __restrict__ w1, const float* __restrict__ w2,
    const float* __restrict__ w3, _Float16* __restrict__ wb)
{
    const int gtid = blockIdx.x * 256 + threadIdx.x;
    for (int i = gtid; i < WB_HALVES; i += 32 * 256) {
        float v;
        if (i < 4224) {                     // w2h [och16][264]
            int och = i / 264, k = i - och * 264;
            int tap = k >> 3, c = k & 7;
            v = (och < 10 && c < 5 && tap < 30) ? w2[(tap * 5 + c) * 10 + och] : 0.f;
        } else if (i < 11904) {             // wph [(c,dlt)][96]
            int j = i - 4224;
            int c = j / 1536, r = j - c * 1536;
            int dlt = r / 96, u = r - dlt * 96;
            int t = u - dlt;
            v = (t >= 0 && t < K1) ? w1[t * C1 + c] : 0.f;
        } else {                            // w3t [oc32][384]
            int j = i - 11904;
            int oc = j / 384, jj = j - oc * 384;
            v = (oc < 20 && jj < 370) ? w3[jj * C3 + oc] : 0.f;
        }
        wb[i] = (_Float16)v;
    }
}

// ---------------- Kernel 1: conv pipeline ----------------
__global__ __launch_bounds__(256, 4) void conv_rows_kernel(
    const float* __restrict__ x,
    const _Float16* __restrict__ wb,
    const float* __restrict__ b1, const float* __restrict__ g1, const float* __restrict__ be1,
    const float* __restrict__ b2, const float* __restrict__ g2, const float* __restrict__ be2,
    const float* __restrict__ b3, const float* __restrict__ g3, const float* __restrict__ be3,
    float* __restrict__ feats, int nrows)
{
    __shared__ __align__(16) char smem[SMEM_BYTES];

    const int tid  = threadIdx.x;
    const int wave = tid >> 6;
    const int lane = tid & 63;

    _Float16* const s1h  = (_Float16*)smem;
    _Float16* const s2h  = (_Float16*)(smem + 18432);
    _Float16* const x16h = (_Float16*)(smem + 18432);   // P0-P1 (first 5120B of s2h region)
    _Float16* const w2h  = (_Float16*)(smem + 23552);   // P0 .. top of P2 (5280B)
    float*    const scr  = (float*)smem;                // aliases s1h (P3 only)

    const int dlt = lane & 15;
    const int grp = lane >> 4;

    // ---- P0: copy w2h global->LDS, stage x16, zero s1h tail ----
    {
        const f32x4* src = (const f32x4*)wb;
        f32x4* dst = (f32x4*)(smem + 23552);
        for (int i = tid; i < 330; i += 256) dst[i] = src[i];   // w2h 5280 B
    }
    {
        unsigned int* x16u = (unsigned int*)x16h;
        const int row0g = blockIdx.x * RPB;
        for (int q = tid; q < 16 * 80; q += 256) {
            int r = q / 80, wp = q - r * 80;
            int gr = row0g + r; if (gr >= nrows) gr = nrows - 1;
            float a = 0.f, b = 0.f;
            if (wp < 65) { const float* xp = x + (size_t)gr * WIN + 2 * wp; a = xp[0]; b = xp[1]; }
            x16u[r * 80 + wp] = pk2h(a, b);
        }
    }
    for (int i = tid; i < 16 * 24; i += 256) {   // s1h halves [528,576) per row = u32 [264,288)
        int r = i / 24, c = i - r * 24;
        ((unsigned int*)s1h)[r * 288 + 264 + c] = 0u;
    }
    __syncthreads();

    // ---- P1: conv1 toeplitz MFMA (B-frags direct from global/L1) ----
    for (int g = wave; g < 5; g += (wave == 1 ? 3 : 5)) {
        const int p0 = g * 16;
        const _Float16* xb = x16h + dlt * 160 + p0 + grp * 8;
        f16x8 a0 = *(const f16x8*)(xb);
        f16x8 a1 = *(const f16x8*)(xb + 32);
        f16x8 a2 = *(const f16x8*)(xb + 64);
        f32x4 o[C1];
        #pragma unroll
        for (int c = 0; c < C1; ++c) {
            const _Float16* wbp = wb + 4224 + (c * 16 + dlt) * 96 + grp * 8;
            f32x4 t = splat4(0.f);
            t = __builtin_amdgcn_mfma_f32_16x16x32_f16(a0, *(const f16x8*)(wbp),      t, 0, 0, 0);
            t = __builtin_amdgcn_mfma_f32_16x16x32_f16(a1, *(const f16x8*)(wbp + 32), t, 0, 0, 0);
            t = __builtin_amdgcn_mfma_f32_16x16x32_f16(a2, *(const f16x8*)(wbp + 64), t, 0, 0, 0);
            o[c] = t + splat4(b1[c]);
        }
        f32x4 m = splat4(0.f);
        #pragma unroll
        for (int c = 0; c < C1; ++c) m += o[c];
        m *= 0.2f;
        f32x4 v = splat4(0.f);
        #pragma unroll
        for (int c = 0; c < C1; ++c) { f32x4 d = o[c] - m; v = pkfma4(d, d, v); }
        f32x4 inv = rsqrt4(v * 0.2f + 1e-3f);
        f32x4 oo[C1];
        #pragma unroll
        for (int c = 0; c < C1; ++c) oo[c] = elu4((o[c] - m) * inv * g1[c] + be1[c]);
        const int p = p0 + dlt;
        if (p < WO1) {
            #pragma unroll
            for (int i = 0; i < 4; ++i) {
                const int row = grp * 4 + i;
                union { _Float16 h[8]; f16x8 v8; } pkv;
                pkv.h[0] = (_Float16)oo[0][i];
                pkv.h[1] = (_Float16)oo[1][i];
                pkv.h[2] = (_Float16)oo[2][i];
                pkv.h[3] = (_Float16)oo[3][i];
                pkv.h[4] = (_Float16)oo[4][i];
                pkv.h[5] = (_Float16)0.f;
                pkv.h[6] = (_Float16)0.f;
                pkv.h[7] = (_Float16)0.f;
                *(f16x8*)&s1h[row * S1H_STRIDE + p * 8] = pkv.v8;
            }
        }
    }
    __syncthreads();

    // ---- P2: conv2 MFMA + LN2 -> s2h (f16) ----
    {
        // B-frags (rows dlt>=10 read stale/garbage LDS; D-rows mk-masked) and A-window
        // preload BEFORE the inner barrier; s2h writes only after it.
        const _Float16* wbase = w2h + dlt * W2H_STRIDE + grp * 8;
        f16x8 wf0 = *(const f16x8*)(wbase);
        f16x8 wf1 = *(const f16x8*)(wbase + 32);
        f16x8 wf2 = *(const f16x8*)(wbase + 64);
        f16x8 wf3 = *(const f16x8*)(wbase + 96);
        f16x8 wf4 = *(const f16x8*)(wbase + 128);
        f16x8 wf5 = *(const f16x8*)(wbase + 160);
        f16x8 wf6 = *(const f16x8*)(wbase + 192);
        f16x8 wf7 = *(const f16x8*)(wbase + 224);

        float b2r[4], g2r[4], be2r[4];
        bool  mk[4];
        #pragma unroll
        for (int i = 0; i < 4; ++i) {
            int oo = grp * 4 + i;
            mk[i] = oo < 10;
            int oc = mk[i] ? oo : 9;
            b2r[i] = b2[oc]; g2r[i] = g2[oc]; be2r[i] = be2[oc];
        }
        const int r  = lane & 3;
        const int pr = (lane >> 2) & 3;
        // A-chunk c (= g+j): 8 halves at row r, offset 32c + 8*(pr+grp)
        const _Float16* arow = s1h + (4 * wave + r) * S1H_STRIDE + (pr + grp) * 8;

        f16x8 ch[17];
        #pragma unroll
        for (int c = 0; c < 8; ++c) ch[c] = *(const f16x8*)(arow + c * 32);

        __syncthreads();   // all waves done reading w2h; s2h region now writable

        unsigned int* s2u = (unsigned int*)s2h;
        if (lane < 44) {
            int r4 = lane / 11, jj = lane - r4 * 11;
            s2u[(4 * wave + r4) * 196 + 185 + jj] = 0u;
        }

        #pragma unroll
        for (int g = 0; g < 10; ++g) {
            if (g + 8 <= 16) ch[g + 8] = *(const f16x8*)(arow + (g + 8) * 32);

            f32x4 aA = splat4(0.f), aB = splat4(0.f);
            aA = __builtin_amdgcn_mfma_f32_16x16x32_f16(wf0, ch[g + 0], aA, 0, 0, 0);
            aB = __builtin_amdgcn_mfma_f32_16x16x32_f16(wf1, ch[g + 1], aB, 0, 0, 0);
            aA = __builtin_amdgcn_mfma_f32_16x16x32_f16(wf2, ch[g + 2], aA, 0, 0, 0);
            aB = __builtin_amdgcn_mfma_f32_16x16x32_f16(wf3, ch[g + 3], aB, 0, 0, 0);
            aA = __builtin_amdgcn_mfma_f32_16x16x32_f16(wf4, ch[g + 4], aA, 0, 0, 0);
            aB = __builtin_amdgcn_mfma_f32_16x16x32_f16(wf5, ch[g + 5], aB, 0, 0, 0);
            aA = __builtin_amdgcn_mfma_f32_16x16x32_f16(wf6, ch[g + 6], aA, 0, 0, 0);
            aB = __builtin_amdgcn_mfma_f32_16x16x32_f16(wf7, ch[g + 7], aB, 0, 0, 0);
            f32x4 acc = aA + aB;

            float v0 = acc.x + b2r[0], v1 = acc.y + b2r[1];
            float v2 = acc.z + b2r[2], v3 = acc.w + b2r[3];
            float sp = (mk[0] ? v0 : 0.f) + (mk[1] ? v1 : 0.f)
                     + (mk[2] ? v2 : 0.f) + (mk[3] ? v3 : 0.f);
            sp += __shfl_xor(sp, 16);
            sp += __shfl_xor(sp, 32);
            const float mean = sp * 0.1f;
            float d0 = v0 - mean, d1 = v1 - mean, d2 = v2 - mean, d3 = v3 - mean;
            float sq = (mk[0] ? d0 * d0 : 0.f) + (mk[1] ? d1 * d1 : 0.f)
                     + (mk[2] ? d2 * d2 : 0.f) + (mk[3] ? d3 * d3 : 0.f);
            sq += __shfl_xor(sq, 16);
            sq += __shfl_xor(sq, 32);
            const float inv = rsqrtf(sq * 0.1f + 1e-3f);

            const int p = g * 4 + pr;
            if (p < WO2) {
                float e0 = elu_f(d0 * inv * g2r[0] + be2r[0]);
                float e1 = elu_f(d1 * inv * g2r[1] + be2r[1]);
                float e2 = elu_f(d2 * inv * g2r[2] + be2r[2]);
                float e3 = elu_f(d3 * inv * g2r[3] + be2r[3]);
                int base = (4 * wave + r) * 196 + p * 5 + grp * 2;
                if (mk[0]) s2u[base]     = pk2h(e0, e1);
                if (mk[2]) s2u[base + 1] = pk2h(e2, e3);
            }
        }
    }
    __syncthreads();

    // ---- P3: conv3 MFMA + LN3 -> feats (scr aliases dead s1h) ----
    {
        const int tile  = wave & 1;
        const int khalf = wave >> 1;
        const int col   = lane & 15;

        const _Float16* arow = s2h + col * 392 + (lane >> 4) * 8;
        const _Float16* brow = wb + 11904 + (size_t)(tile * 16 + col) * 384 + (lane >> 4) * 8;

        f32x4 acc = splat4(0.f);
        #pragma unroll
        for (int s = 0; s < 6; ++s) {
            const int st = khalf * 6 + s;
            f16x8 af = *(const f16x8*)(arow + st * 32);
            f16x8 bf = *(const f16x8*)(brow + st * 32);
            acc = __builtin_amdgcn_mfma_f32_16x16x32_f16(af, bf, acc, 0, 0, 0);
        }
        f32x4* scrv = (f32x4*)scr;
        if (khalf == 1) scrv[tile * 64 + lane] = acc;
        __syncthreads();

        const int ocg = tile * 16 + col;
        const bool vc = ocg < 20;
        const int occ = vc ? ocg : 19;
        f32x4 vv = splat4(0.f);
        float* sums = scr + 512;
        if (khalf == 0) {
            acc += scrv[tile * 64 + lane];
            vv = acc + splat4(b3[occ]);
            if (!vc) vv = splat4(0.f);
            f32x4 s = vv, q = vv * vv;
            #pragma unroll
            for (int d = 1; d < 16; d <<= 1) {
                s.x += __shfl_xor(s.x, d); s.y += __shfl_xor(s.y, d);
                s.z += __shfl_xor(s.z, d); s.w += __shfl_xor(s.w, d);
                q.x += __shfl_xor(q.x, d); q.y += __shfl_xor(q.y, d);
                q.z += __shfl_xor(q.z, d); q.w += __shfl_xor(q.w, d);
            }
            if (col == 0) {
                const int rb = (lane >> 4) * 4;
                #pragma unroll
                for (int i = 0; i < 4; ++i) {
                    sums[tile * 64 + rb + i]      = s[i];
                    sums[tile * 64 + 16 + rb + i] = q[i];
                }
            }
        }
        __syncthreads();
        if (khalf == 0) {
            const float gg = g3[occ], bb = be3[occ];
            #pragma unroll
            for (int i = 0; i < 4; ++i) {
                const int row = (lane >> 4) * 4 + i;
                const float ts = sums[row] + sums[64 + row];
                const float tq = sums[16 + row] + sums[80 + row];
                const float mn = ts * 0.05f;
                const float vr = tq * 0.05f - mn * mn;
                const float iv = rsqrtf(vr + 1e-3f);
                if (vc) {
                    const int grow = blockIdx.x * RPB + row;
                    if (grow < nrows)
                        feats[(size_t)grow * C3 + ocg] = elu_f((vv[i] - mn) * iv * gg + bb);
                }
            }
        }
    }
}

// ---------------- Kernel 2: per-batch graph block, MFMA + symmetric corr ----------------
__global__ __launch_bounds__(256) void graph_kernel(
    const float* __restrict__ feats,
    const float* __restrict__ agent_w, const float* __restrict__ agent_b,
    const float* __restrict__ g1w, const float* __restrict__ g1b,
    const float* __restrict__ g2w, const float* __restrict__ g2b,
    const float* __restrict__ dw, const float* __restrict__ db,
    const int* __restrict__ rlp,
    float* __restrict__ out)
{
    __shared__ __align__(16) char gsm[61104];
    _Float16* const sLh  = (_Float16*)(gsm);
    _Float16* const sfcH = (_Float16*)(gsm + 34816);
    float*    const h2T  = (float*)(gsm + 34816);
    float*    const sfe  = (float*)(gsm + 45056);
    float*    const h1f  = (float*)(gsm + 45056);
    _Float16* const t1h  = (_Float16*)(gsm + 54176);
    float* const snrm  = (float*)(gsm + 58528);
    float* const sidx  = (float*)(gsm + 58984);
    float* const sdv   = (float*)(gsm + 59440);
    float* const red   = (float*)(gsm + 59896);
    float* const sfeat = (float*)(gsm + 59912);
    float* const sg1   = (float*)(gsm + 59952);
    float* const sg1b  = sg1 + 200;
    float* const sg2   = sg1b + 10;
    float* const sg2b  = sg2 + 50;
    float* const sdw   = sg2b + 5;
    float* const sdb   = sdw + 20;

    const int tid  = threadIdx.x;
    const int wave = tid >> 6;
    const int lane = tid & 63;
    const int b = blockIdx.x;
    const float* F = feats + (size_t)b * (NN * C3);
    const int rl = rlp[0];
    const float aw_b = agent_b[0];

    // ---- P0 ----
    {
        f32x4* z = (f32x4*)gsm;
        for (int i = tid; i < 2816; i += 256) z[i] = splat4(0.f);
        f32x4* z2 = (f32x4*)(gsm + 54176);
        if (tid < 272) z2[tid] = splat4(0.f);
        if (tid < 200) sg1[tid] = g1w[tid];
        if (tid < 10)  sg1b[tid] = g1b[tid];
        if (tid < 50)  sg2[tid] = g2w[tid];
        if (tid < 5)   sg2b[tid] = g2b[tid];
        if (tid < 20)  sdw[tid] = dw[tid];
        if (tid < 2)   sdb[tid] = db[tid];
    }
    __syncthreads();

    // ---- P1 ----
    for (int n = tid; n < NN; n += 256) {
        float f[C3];
        float m = 0.f;
        #pragma unroll
        for (int d = 0; d < C3; ++d) { f[d] = F[n * C3 + d]; m += f[d]; }
        m *= (1.f / C3);
        float nr = 0.f, ag = 0.f;
        unsigned int* dst = (unsigned int*)(sfcH + n * 40);
        #pragma unroll
        for (int d = 0; d < C3; d += 2) {
            sfe[n * C3 + d]     = f[d];
            sfe[n * C3 + d + 1] = f[d + 1];
            float c0 = f[d] - m, c1 = f[d + 1] - m;
            dst[d >> 1] = pk2h(c0, c1);
            nr = fmaf(c0, c0, fmaf(c1, c1, nr));
            ag = fmaf(f[d], agent_w[d], fmaf(f[d + 1], agent_w[d + 1], ag));
        }
        snrm[n] = sqrtf(nr);
        sidx[n] = rl ? (1.f / (1.f + __expf(-(ag + aw_b)))) : 1.f;
    }
    __syncthreads();

    // ---- P2: corr via MFMA, upper-triangular tiles (36), mirror stores ----
    {
        float psum = 0.f;
        const int row = lane & 15;
        const int kg  = lane >> 4;
        for (int tt = 0; tt < 9; ++tt) {
            int idx = wave * 9 + tt;            // 0..35 over 4 waves
            int tr = 0, rem = idx;
            while (rem >= 8 - tr) { rem -= 8 - tr; ++tr; }
            const int tc = tr + rem;
            f16x8 a  = *(const f16x8*)(sfcH + (tr * 16 + row) * 40 + kg * 8);
            f16x8 bf = *(const f16x8*)(sfcH + (tc * 16 + row) * 40 + kg * 8);
            f32x4 acc = __builtin_amdgcn_mfma_f32_16x16x32_f16(a, bf, splat4(0.f), 0, 0, 0);
            const int c = tc * 16 + row;
            const float nc = (c < NN) ? snrm[c] : 1.f;
            const float wgt = (tr == tc) ? 1.f : 2.f;
            const bool mirror = (tr != tc);
            #pragma unroll
            for (int i = 0; i < 4; ++i) {
                const int r = tr * 16 + kg * 4 + i;
                float dist = 0.f;
                if (r < NN && c < NN && r != c)
                    dist = 1.f - acc[i] * __frcp_rn(snrm[r] * nc);
                psum += wgt * dist;
                sLh[r * 136 + c] = (_Float16)dist;
                if (mirror) sLh[c * 136 + r] = (_Float16)dist;
            }
        }
        #pragma unroll
        for (int d = 1; d < 64; d <<= 1) psum += __shfl_xor(psum, d);
        if (lane == 0) red[wave] = psum;
    }
    __syncthreads();

    // ---- P3 ----
    {
        const float sg = (red[0] + red[1] + red[2] + red[3]) * (1.f / (float)(NN * NN));
        const float inv2s2 = 1.f / (2.f * sg * sg);
        if (tid < 228) {
            const int r = tid >> 1, half = tid & 1;
            const float idxr = sidx[r];
            float rsum = 0.f;
            _Float16* rp = sLh + r * 136 + half * 57;
            const int c0 = half * 57;
            for (int j = 0; j < 57; ++j) {
                float d = (float)rp[j];
                float A = idxr * sidx[c0 + j] * __expf(-d * d * inv2s2);
                rsum += A;
                rp[j] = (_Float16)A;
            }
            rsum += __shfl_xor(rsum, 1);
            if (half == 0) {
                float dv = rsqrtf(rsum);
                if (isinf(dv)) dv = 0.f;
                sdv[r] = dv;
            }
        }
    }
    __syncthreads();

    // ---- P4 ----
    {
        unsigned int* L32 = (unsigned int*)sLh;
        for (int e2 = tid; e2 < NN * 57; e2 += 256) {
            const int r = e2 / 57, cp = e2 - r * 57;
            const unsigned int u = L32[r * 68 + cp];
            union { unsigned int uu; _Float16 h[2]; } in;
            in.uu = u;
            const float dr = sdv[r];
            float v0 = (float)in.h[0] * dr * sdv[2 * cp];
            float v1 = (float)in.h[1] * dr * sdv[2 * cp + 1];
            L32[r * 68 + cp] = pk2h(v0, v1);
        }
        for (int e = tid; e < NN * C2; e += 256) {
            const int n = e / C2, o = e - n * C2;
            float acc = 0.f;
            #pragma unroll
            for (int d = 0; d < C3; ++d) acc = fmaf(sfe[n * C3 + d], sg1[d * C2 + o], acc);
            t1h[o * 136 + n] = (_Float16)(acc * sidx[n] + sg1b[o]);
        }
    }
    __syncthreads();

    // ---- P5 ----
    {
        const int row = lane & 15;
        const int kg  = lane >> 4;
        #pragma unroll
        for (int tt = 0; tt < 2; ++tt) {
            const int tr = wave * 2 + tt;
            f32x4 acc = splat4(0.f);
            #pragma unroll
            for (int ks = 0; ks < 4; ++ks) {
                f16x8 a = *(const f16x8*)(sLh + (tr * 16 + row) * 136 + ks * 32 + kg * 8);
                f16x8 bf = *(const f16x8*)(t1h + row * 136 + ks * 32 + kg * 8);
                acc = __builtin_amdgcn_mfma_f32_16x16x32_f16(a, bf, acc, 0, 0, 0);
            }
            #pragma unroll
            for (int i = 0; i < 4; ++i) {
                const int n = tr * 16 + kg * 4 + i;
                h1f[n * 16 + row] = elu_f(acc[i]);
            }
        }
    }
    __syncthreads();

    // ---- P6 ----
    for (int e = tid; e < NN * C1; e += 256) {
        const int n = e / C1, c = e - n * C1;
        float acc = sg2b[c];
        #pragma unroll
        for (int o = 0; o < C2; ++o) acc = fmaf(h1f[n * 16 + o], sg2[o * C1 + c], acc);
        t1h[c * 136 + n] = (_Float16)acc;
    }
    __syncthreads();

    // ---- P7 ----
    {
        const int row = lane & 15;
        const int kg  = lane >> 4;
        #pragma unroll
        for (int tt = 0; tt < 2; ++tt) {
            const int tr = wave * 2 + tt;
            f32x4 acc = splat4(0.f);
            #pragma unroll
            for (int ks = 0; ks < 4; ++ks) {
                f16x8 a = *(const f16x8*)(sLh + (tr * 16 + row) * 136 + ks * 32 + kg * 8);
                f16x8 bf = *(const f16x8*)(t1h + row * 136 + ks * 32 + kg * 8);
                acc = __builtin_amdgcn_mfma_f32_16x16x32_f16(a, bf, acc, 0, 0, 0);
            }
            if (row < C1) {
                #pragma unroll
                for (int i = 0; i < 4; ++i) {
                    const int n = tr * 16 + kg * 4 + i;
                    h2T[row * 132 + n] = elu_f(acc[i]);
                }
            }
        }
    }
    __syncthreads();

    // ---- P8 ----
    if (tid < 160) {
        const int c = tid >> 5, s = tid & 31;
        float pmax = -INFINITY, rmin = INFINITY, sum = 0.f;
        #pragma unroll
        for (int k = 0; k < 4; ++k) {
            const int n = s + 32 * k;
            if (n < NN) {
                float v = h2T[c * 132 + n];
                pmax = fmaxf(pmax, v);
                rmin = fminf(rmin, 1.f / v);
                sum += v;
            }
        }
        #pragma unroll
        for (int d = 16; d > 0; d >>= 1) {
            pmax = fmaxf(pmax, __shfl_xor(pmax, d));
            rmin = fminf(rmin, __shfl_xor(rmin, d));
            sum += __shfl_xor(sum, d);
        }
        if (s == 0) {
            float nmax = 1.f / rmin;
            sfeat[c] = (pmax == 0.f) ? nmax : pmax;
            sfeat[C1 + c] = sum;
        }
    }
    __syncthreads();

    if (tid == 0) {
        float l0 = sdb[0], l1 = sdb[1];
        #pragma unroll
        for (int j = 0; j < 10; ++j) {
            l0 += sfeat[j] * sdw[j * 2 + 0];
            l1 += sfeat[j] * sdw[j * 2 + 1];
        }
        float mx = fmaxf(l0, l1);
        float e0 = expf(l0 - mx), e1 = expf(l1 - mx);
        float s = e0 + e1;
        out[b * 2 + 0] = e0 / s;
        out[b * 2 + 1] = e1 / s;
    }
}

extern "C" void kernel_launch(void* const* d_in, const int* in_sizes, int n_in,
                              void* d_out, int out_size, void* d_ws, size_t ws_size,
                              hipStream_t stream) {
    const float* x       = (const float*)d_in[0];
    const float* conv1_w = (const float*)d_in[1];
    const float* conv1_b = (const float*)d_in[2];
    const float* ln1_g   = (const float*)d_in[3];
    const float* ln1_b   = (const float*)d_in[4];
    const float* conv2_w = (const float*)d_in[5];
    const float* conv2_b = (const float*)d_in[6];
    const float* ln2_g   = (const float*)d_in[7];
    const float* ln2_b   = (const float*)d_in[8];
    const float* conv3_w = (const float*)d_in[9];
    const float* conv3_b = (const float*)d_in[10];
    const float* ln3_g   = (const float*)d_in[11];
    const float* ln3_b   = (const float*)d_in[12];
    const float* agent_w = (const float*)d_in[13];
    const float* agent_b = (const float*)d_in[14];
    const float* gconv1_w= (const float*)d_in[15];
    const float* gconv1_b= (const float*)d_in[16];
    const float* gconv2_w= (const float*)d_in[17];
    const float* gconv2_b= (const float*)d_in[18];
    const float* dense_w = (const float*)d_in[19];
    const float* dense_b = (const float*)d_in[20];
    const int*   rl      = (const int*)d_in[21];
    float* out = (float*)d_out;

    const int B = in_sizes[0] / (NH * WIN);
    const int nrows = B * NH;
    _Float16* wbuf = (_Float16*)d_ws;
    float* feats = (float*)((char*)d_ws + FEATS_OFF);

    dim3 block(256);
    hipLaunchKernelGGL(prep_kernel, dim3(32), block, 0, stream,
                       conv1_w, conv2_w, conv3_w, wbuf);

    dim3 grid1((nrows + RPB - 1) / RPB);
    hipLaunchKernelGGL(conv_rows_kernel, grid1, block, 0, stream,
                       x, (const _Float16*)wbuf,
                       conv1_b, ln1_g, ln1_b,
                       conv2_b, ln2_g, ln2_b,
                       conv3_b, ln3_g, ln3_b,
                       feats, nrows);

    dim3 grid2(B);
    hipLaunchKernelGGL(graph_kernel, grid2, block, 0, stream,
                       feats, agent_w, agent_b,
                       gconv1_w, gconv1_b, gconv2_w, gconv2_b,
                       dense_w, dense_b, rl, out);
}

// Round 16
// 162.667 us; speedup vs baseline: 1.1092x; 1.0108x over previous
//
#include <hip/hip_runtime.h>
#include <math.h>

#define NH    114
#define WIN   130
#define WO1   66
#define WO2   37
#define C1    5
#define C2    10
#define C3    20
#define K1    65
#define K2    30
#define K3    37
#define NN    114
#define RPB   16     // rows per block = 4 waves; row-quads per wave

typedef float f32x4 __attribute__((ext_vector_type(4)));
typedef _Float16 f16x8 __attribute__((ext_vector_type(8)));

// ---- d_ws layout ----
#define WB_HALVES 24192
#define FEATS_OFF 65536

// ---- conv LDS layout (bytes), total 30976 ----
//  [0,     18432): s1h  16 x 576 f16 (pos 0..65 real, 66..71 zero) | P3: scr f32 aliases at 0
//  [18432, 30976): s2h  16 x 392 f16 (P2 after inner barrier, P3)
//      time-multiplexed within s2h footprint:
//      [18432, 23552): x16h 16 x 160 f16   (P0-P1)
//      [23552, 28832): w2h  10 x 264 f16   (P0 copy .. top of P2; regs by inner barrier)
#define SMEM_BYTES 30976
#define S1H_STRIDE 576
#define W2H_STRIDE 264

__device__ __forceinline__ f32x4 splat4(float s) { f32x4 r; r.x = s; r.y = s; r.z = s; r.w = s; return r; }
__device__ __forceinline__ f32x4 pkfma4(f32x4 a, f32x4 b, f32x4 c) {
    return __builtin_elementwise_fma(a, b, c);
}
__device__ __forceinline__ float elu_f(float v) { return fmaxf(v, 0.f) + __expf(fminf(v, 0.f)) - 1.f; }
__device__ __forceinline__ f32x4 elu4(f32x4 v) {
    f32x4 r;
    r.x = elu_f(v.x); r.y = elu_f(v.y); r.z = elu_f(v.z); r.w = elu_f(v.w);
    return r;
}
__device__ __forceinline__ f32x4 rsqrt4(f32x4 v) {
    f32x4 r; r.x = rsqrtf(v.x); r.y = rsqrtf(v.y); r.z = rsqrtf(v.z); r.w = rsqrtf(v.w);
    return r;
}
__device__ __forceinline__ unsigned int pk2h(float a, float b) {
    union { _Float16 h[2]; unsigned int u; } v;
    v.h[0] = (_Float16)a; v.h[1] = (_Float16)b; return v.u;
}

// ---------------- prep kernel: format weights to f16 once ----------------
__global__ __launch_bounds__(256) void prep_kernel(
    const float* __restrict__ w1, const float* __restrict__ w2,
    const float* __restrict__ w3, _Float16* __restrict__ wb)
{
    const int gtid = blockIdx.x * 256 + threadIdx.x;
    for (int i = gtid; i < WB_HALVES; i += 32 * 256) {
        float v;
        if (i < 4224) {                     // w2h [och16][264]
            int och = i / 264, k = i - och * 264;
            int tap = k >> 3, c = k & 7;
            v = (och < 10 && c < 5 && tap < 30) ? w2[(tap * 5 + c) * 10 + och] : 0.f;
        } else if (i < 11904) {             // wph [(c,dlt)][96]
            int j = i - 4224;
            int c = j / 1536, r = j - c * 1536;
            int dlt = r / 96, u = r - dlt * 96;
            int t = u - dlt;
            v = (t >= 0 && t < K1) ? w1[t * C1 + c] : 0.f;
        } else {                            // w3t [oc32][384]
            int j = i - 11904;
            int oc = j / 384, jj = j - oc * 384;
            v = (oc < 20 && jj < 370) ? w3[jj * C3 + oc] : 0.f;
        }
        wb[i] = (_Float16)v;
    }
}

// ---------------- Kernel 1: conv pipeline ----------------
__global__ __launch_bounds__(256, 4) void conv_rows_kernel(
    const float* __restrict__ x,
    const _Float16* __restrict__ wb,
    const float* __restrict__ b1, const float* __restrict__ g1, const float* __restrict__ be1,
    const float* __restrict__ b2, const float* __restrict__ g2, const float* __restrict__ be2,
    const float* __restrict__ b3, const float* __restrict__ g3, const float* __restrict__ be3,
    float* __restrict__ feats, int nrows)
{
    __shared__ __align__(16) char smem[SMEM_BYTES];

    const int tid  = threadIdx.x;
    const int wave = tid >> 6;
    const int lane = tid & 63;

    _Float16* const s1h  = (_Float16*)smem;
    _Float16* const s2h  = (_Float16*)(smem + 18432);
    _Float16* const x16h = (_Float16*)(smem + 18432);   // P0-P1 (first 5120B of s2h region)
    _Float16* const w2h  = (_Float16*)(smem + 23552);   // P0 .. top of P2 (5280B)
    float*    const scr  = (float*)smem;                // aliases s1h (P3 only)

    const int dlt = lane & 15;
    const int grp = lane >> 4;

    // ---- P0: copy w2h global->LDS, stage x16, zero s1h tail ----
    {
        const f32x4* src = (const f32x4*)wb;
        f32x4* dst = (f32x4*)(smem + 23552);
        for (int i = tid; i < 330; i += 256) dst[i] = src[i];   // w2h 5280 B
    }
    {
        unsigned int* x16u = (unsigned int*)x16h;
        const int row0g = blockIdx.x * RPB;
        for (int q = tid; q < 16 * 80; q += 256) {
            int r = q / 80, wp = q - r * 80;
            int gr = row0g + r; if (gr >= nrows) gr = nrows - 1;
            float a = 0.f, b = 0.f;
            if (wp < 65) { const float* xp = x + (size_t)gr * WIN + 2 * wp; a = xp[0]; b = xp[1]; }
            x16u[r * 80 + wp] = pk2h(a, b);
        }
    }
    for (int i = tid; i < 16 * 24; i += 256) {   // s1h halves [528,576) per row = u32 [264,288)
        int r = i / 24, c = i - r * 24;
        ((unsigned int*)s1h)[r * 288 + 264 + c] = 0u;
    }
    __syncthreads();

    // ---- P1: conv1 toeplitz MFMA (B-frags direct from global/L1) ----
    for (int g = wave; g < 5; g += (wave == 1 ? 3 : 5)) {
        const int p0 = g * 16;
        const _Float16* xb = x16h + dlt * 160 + p0 + grp * 8;
        f16x8 a0 = *(const f16x8*)(xb);
        f16x8 a1 = *(const f16x8*)(xb + 32);
        f16x8 a2 = *(const f16x8*)(xb + 64);
        f32x4 o[C1];
        #pragma unroll
        for (int c = 0; c < C1; ++c) {
            const _Float16* wbp = wb + 4224 + (c * 16 + dlt) * 96 + grp * 8;
            f32x4 t = splat4(0.f);
            t = __builtin_amdgcn_mfma_f32_16x16x32_f16(a0, *(const f16x8*)(wbp),      t, 0, 0, 0);
            t = __builtin_amdgcn_mfma_f32_16x16x32_f16(a1, *(const f16x8*)(wbp + 32), t, 0, 0, 0);
            t = __builtin_amdgcn_mfma_f32_16x16x32_f16(a2, *(const f16x8*)(wbp + 64), t, 0, 0, 0);
            o[c] = t + splat4(b1[c]);
        }
        f32x4 m = splat4(0.f);
        #pragma unroll
        for (int c = 0; c < C1; ++c) m += o[c];
        m *= 0.2f;
        f32x4 v = splat4(0.f);
        #pragma unroll
        for (int c = 0; c < C1; ++c) { f32x4 d = o[c] - m; v = pkfma4(d, d, v); }
        f32x4 inv = rsqrt4(v * 0.2f + 1e-3f);
        f32x4 oo[C1];
        #pragma unroll
        for (int c = 0; c < C1; ++c) oo[c] = elu4((o[c] - m) * inv * g1[c] + be1[c]);
        const int p = p0 + dlt;
        if (p < WO1) {
            #pragma unroll
            for (int i = 0; i < 4; ++i) {
                const int row = grp * 4 + i;
                union { _Float16 h[8]; f16x8 v8; } pkv;
                pkv.h[0] = (_Float16)oo[0][i];
                pkv.h[1] = (_Float16)oo[1][i];
                pkv.h[2] = (_Float16)oo[2][i];
                pkv.h[3] = (_Float16)oo[3][i];
                pkv.h[4] = (_Float16)oo[4][i];
                pkv.h[5] = (_Float16)0.f;
                pkv.h[6] = (_Float16)0.f;
                pkv.h[7] = (_Float16)0.f;
                *(f16x8*)&s1h[row * S1H_STRIDE + p * 8] = pkv.v8;
            }
        }
    }
    __syncthreads();

    // ---- P2: conv2 MFMA + LN2 -> s2h (f16), 2-stage software pipeline ----
    {
        // B-frags (rows dlt>=10 read stale/garbage LDS; D-rows mk-masked) and A-window
        // preload BEFORE the inner barrier; s2h writes only after it.
        const _Float16* wbase = w2h + dlt * W2H_STRIDE + grp * 8;
        f16x8 wf0 = *(const f16x8*)(wbase);
        f16x8 wf1 = *(const f16x8*)(wbase + 32);
        f16x8 wf2 = *(const f16x8*)(wbase + 64);
        f16x8 wf3 = *(const f16x8*)(wbase + 96);
        f16x8 wf4 = *(const f16x8*)(wbase + 128);
        f16x8 wf5 = *(const f16x8*)(wbase + 160);
        f16x8 wf6 = *(const f16x8*)(wbase + 192);
        f16x8 wf7 = *(const f16x8*)(wbase + 224);

        float b2r[4], g2r[4], be2r[4];
        bool  mk[4];
        #pragma unroll
        for (int i = 0; i < 4; ++i) {
            int oo = grp * 4 + i;
            mk[i] = oo < 10;
            int oc = mk[i] ? oo : 9;
            b2r[i] = b2[oc]; g2r[i] = g2[oc]; be2r[i] = be2[oc];
        }
        const int r  = lane & 3;
        const int pr = (lane >> 2) & 3;
        // A-chunk c (= g+j): 8 halves at row r, offset 32c + 8*(pr+grp)
        const _Float16* arow = s1h + (4 * wave + r) * S1H_STRIDE + (pr + grp) * 8;

        f16x8 ch[17];
        #pragma unroll
        for (int c = 0; c < 9; ++c) ch[c] = *(const f16x8*)(arow + c * 32);

        __syncthreads();   // all waves done reading w2h; s2h region now writable

        unsigned int* s2u = (unsigned int*)s2h;
        if (lane < 44) {
            int r4 = lane / 11, jj = lane - r4 * 11;
            s2u[(4 * wave + r4) * 196 + 185 + jj] = 0u;
        }

        // prologue: accumulators for g=0
        f32x4 curA = splat4(0.f), curB = splat4(0.f);
        curA = __builtin_amdgcn_mfma_f32_16x16x32_f16(wf0, ch[0], curA, 0, 0, 0);
        curB = __builtin_amdgcn_mfma_f32_16x16x32_f16(wf1, ch[1], curB, 0, 0, 0);
        curA = __builtin_amdgcn_mfma_f32_16x16x32_f16(wf2, ch[2], curA, 0, 0, 0);
        curB = __builtin_amdgcn_mfma_f32_16x16x32_f16(wf3, ch[3], curB, 0, 0, 0);
        curA = __builtin_amdgcn_mfma_f32_16x16x32_f16(wf4, ch[4], curA, 0, 0, 0);
        curB = __builtin_amdgcn_mfma_f32_16x16x32_f16(wf5, ch[5], curB, 0, 0, 0);
        curA = __builtin_amdgcn_mfma_f32_16x16x32_f16(wf6, ch[6], curA, 0, 0, 0);
        curB = __builtin_amdgcn_mfma_f32_16x16x32_f16(wf7, ch[7], curB, 0, 0, 0);

        #pragma unroll
        for (int g = 0; g < 10; ++g) {
            // issue next iteration's MFMAs before this iteration's elementwise chain
            f32x4 nxtA = splat4(0.f), nxtB = splat4(0.f);
            if (g < 8) ch[g + 9] = *(const f16x8*)(arow + (g + 9) * 32);
            if (g < 9) {
                nxtA = __builtin_amdgcn_mfma_f32_16x16x32_f16(wf0, ch[g + 1], nxtA, 0, 0, 0);
                nxtB = __builtin_amdgcn_mfma_f32_16x16x32_f16(wf1, ch[g + 2], nxtB, 0, 0, 0);
                nxtA = __builtin_amdgcn_mfma_f32_16x16x32_f16(wf2, ch[g + 3], nxtA, 0, 0, 0);
                nxtB = __builtin_amdgcn_mfma_f32_16x16x32_f16(wf3, ch[g + 4], nxtB, 0, 0, 0);
                nxtA = __builtin_amdgcn_mfma_f32_16x16x32_f16(wf4, ch[g + 5], nxtA, 0, 0, 0);
                nxtB = __builtin_amdgcn_mfma_f32_16x16x32_f16(wf5, ch[g + 6], nxtB, 0, 0, 0);
                nxtA = __builtin_amdgcn_mfma_f32_16x16x32_f16(wf6, ch[g + 7], nxtA, 0, 0, 0);
                nxtB = __builtin_amdgcn_mfma_f32_16x16x32_f16(wf7, ch[g + 8], nxtB, 0, 0, 0);
            }

            f32x4 acc = curA + curB;

            float v0 = acc.x + b2r[0], v1 = acc.y + b2r[1];
            float v2 = acc.z + b2r[2], v3 = acc.w + b2r[3];
            float sp = (mk[0] ? v0 : 0.f) + (mk[1] ? v1 : 0.f)
                     + (mk[2] ? v2 : 0.f) + (mk[3] ? v3 : 0.f);
            sp += __shfl_xor(sp, 16);
            sp += __shfl_xor(sp, 32);
            const float mean = sp * 0.1f;
            float d0 = v0 - mean, d1 = v1 - mean, d2 = v2 - mean, d3 = v3 - mean;
            float sq = (mk[0] ? d0 * d0 : 0.f) + (mk[1] ? d1 * d1 : 0.f)
                     + (mk[2] ? d2 * d2 : 0.f) + (mk[3] ? d3 * d3 : 0.f);
            sq += __shfl_xor(sq, 16);
            sq += __shfl_xor(sq, 32);
            const float inv = rsqrtf(sq * 0.1f + 1e-3f);

            const int p = g * 4 + pr;
            if (p < WO2) {
                float e0 = elu_f(d0 * inv * g2r[0] + be2r[0]);
                float e1 = elu_f(d1 * inv * g2r[1] + be2r[1]);
                float e2 = elu_f(d2 * inv * g2r[2] + be2r[2]);
                float e3 = elu_f(d3 * inv * g2r[3] + be2r[3]);
                int base = (4 * wave + r) * 196 + p * 5 + grp * 2;
                if (mk[0]) s2u[base]     = pk2h(e0, e1);
                if (mk[2]) s2u[base + 1] = pk2h(e2, e3);
            }

            curA = nxtA; curB = nxtB;
        }
    }
    __syncthreads();

    // ---- P3: conv3 MFMA + LN3 -> feats (scr aliases dead s1h) ----
    {
        const int tile  = wave & 1;
        const int khalf = wave >> 1;
        const int col   = lane & 15;

        const _Float16* arow = s2h + col * 392 + (lane >> 4) * 8;
        const _Float16* brow = wb + 11904 + (size_t)(tile * 16 + col) * 384 + (lane >> 4) * 8;

        f32x4 acc = splat4(0.f);
        #pragma unroll
        for (int s = 0; s < 6; ++s) {
            const int st = khalf * 6 + s;
            f16x8 af = *(const f16x8*)(arow + st * 32);
            f16x8 bf = *(const f16x8*)(brow + st * 32);
            acc = __builtin_amdgcn_mfma_f32_16x16x32_f16(af, bf, acc, 0, 0, 0);
        }
        f32x4* scrv = (f32x4*)scr;
        if (khalf == 1) scrv[tile * 64 + lane] = acc;
        __syncthreads();

        const int ocg = tile * 16 + col;
        const bool vc = ocg < 20;
        const int occ = vc ? ocg : 19;
        f32x4 vv = splat4(0.f);
        float* sums = scr + 512;
        if (khalf == 0) {
            acc += scrv[tile * 64 + lane];
            vv = acc + splat4(b3[occ]);
            if (!vc) vv = splat4(0.f);
            f32x4 s = vv, q = vv * vv;
            #pragma unroll
            for (int d = 1; d < 16; d <<= 1) {
                s.x += __shfl_xor(s.x, d); s.y += __shfl_xor(s.y, d);
                s.z += __shfl_xor(s.z, d); s.w += __shfl_xor(s.w, d);
                q.x += __shfl_xor(q.x, d); q.y += __shfl_xor(q.y, d);
                q.z += __shfl_xor(q.z, d); q.w += __shfl_xor(q.w, d);
            }
            if (col == 0) {
                const int rb = (lane >> 4) * 4;
                #pragma unroll
                for (int i = 0; i < 4; ++i) {
                    sums[tile * 64 + rb + i]      = s[i];
                    sums[tile * 64 + 16 + rb + i] = q[i];
                }
            }
        }
        __syncthreads();
        if (khalf == 0) {
            const float gg = g3[occ], bb = be3[occ];
            #pragma unroll
            for (int i = 0; i < 4; ++i) {
                const int row = (lane >> 4) * 4 + i;
                const float ts = sums[row] + sums[64 + row];
                const float tq = sums[16 + row] + sums[80 + row];
                const float mn = ts * 0.05f;
                const float vr = tq * 0.05f - mn * mn;
                const float iv = rsqrtf(vr + 1e-3f);
                if (vc) {
                    const int grow = blockIdx.x * RPB + row;
                    if (grow < nrows)
                        feats[(size_t)grow * C3 + ocg] = elu_f((vv[i] - mn) * iv * gg + bb);
                }
            }
        }
    }
}

// ---------------- Kernel 2: per-batch graph block, MFMA + symmetric corr ----------------
__global__ __launch_bounds__(256) void graph_kernel(
    const float* __restrict__ feats,
    const float* __restrict__ agent_w, const float* __restrict__ agent_b,
    const float* __restrict__ g1w, const float* __restrict__ g1b,
    const float* __restrict__ g2w, const float* __restrict__ g2b,
    const float* __restrict__ dw, const float* __restrict__ db,
    const int* __restrict__ rlp,
    float* __restrict__ out)
{
    __shared__ __align__(16) char gsm[61104];
    _Float16* const sLh  = (_Float16*)(gsm);
    _Float16* const sfcH = (_Float16*)(gsm + 34816);
    float*    const h2T  = (float*)(gsm + 34816);
    float*    const sfe  = (float*)(gsm + 45056);
    float*    const h1f  = (float*)(gsm + 45056);
    _Float16* const t1h  = (_Float16*)(gsm + 54176);
    float* const snrm  = (float*)(gsm + 58528);
    float* const sidx  = (float*)(gsm + 58984);
    float* const sdv   = (float*)(gsm + 59440);
    float* const red   = (float*)(gsm + 59896);
    float* const sfeat = (float*)(gsm + 59912);
    float* const sg1   = (float*)(gsm + 59952);
    float* const sg1b  = sg1 + 200;
    float* const sg2   = sg1b + 10;
    float* const sg2b  = sg2 + 50;
    float* const sdw   = sg2b + 5;
    float* const sdb   = sdw + 20;

    const int tid  = threadIdx.x;
    const int wave = tid >> 6;
    const int lane = tid & 63;
    const int b = blockIdx.x;
    const float* F = feats + (size_t)b * (NN * C3);
    const int rl = rlp[0];
    const float aw_b = agent_b[0];

    // ---- P0 ----
    {
        f32x4* z = (f32x4*)gsm;
        for (int i = tid; i < 2816; i += 256) z[i] = splat4(0.f);
        f32x4* z2 = (f32x4*)(gsm + 54176);
        if (tid < 272) z2[tid] = splat4(0.f);
        if (tid < 200) sg1[tid] = g1w[tid];
        if (tid < 10)  sg1b[tid] = g1b[tid];
        if (tid < 50)  sg2[tid] = g2w[tid];
        if (tid < 5)   sg2b[tid] = g2b[tid];
        if (tid < 20)  sdw[tid] = dw[tid];
        if (tid < 2)   sdb[tid] = db[tid];
    }
    __syncthreads();

    // ---- P1 ----
    for (int n = tid; n < NN; n += 256) {
        float f[C3];
        float m = 0.f;
        #pragma unroll
        for (int d = 0; d < C3; ++d) { f[d] = F[n * C3 + d]; m += f[d]; }
        m *= (1.f / C3);
        float nr = 0.f, ag = 0.f;
        unsigned int* dst = (unsigned int*)(sfcH + n * 40);
        #pragma unroll
        for (int d = 0; d < C3; d += 2) {
            sfe[n * C3 + d]     = f[d];
            sfe[n * C3 + d + 1] = f[d + 1];
            float c0 = f[d] - m, c1 = f[d + 1] - m;
            dst[d >> 1] = pk2h(c0, c1);
            nr = fmaf(c0, c0, fmaf(c1, c1, nr));
            ag = fmaf(f[d], agent_w[d], fmaf(f[d + 1], agent_w[d + 1], ag));
        }
        snrm[n] = sqrtf(nr);
        sidx[n] = rl ? (1.f / (1.f + __expf(-(ag + aw_b)))) : 1.f;
    }
    __syncthreads();

    // ---- P2: corr via MFMA, upper-triangular tiles (36), mirror stores ----
    {
        float psum = 0.f;
        const int row = lane & 15;
        const int kg  = lane >> 4;
        for (int tt = 0; tt < 9; ++tt) {
            int idx = wave * 9 + tt;            // 0..35 over 4 waves
            int tr = 0, rem = idx;
            while (rem >= 8 - tr) { rem -= 8 - tr; ++tr; }
            const int tc = tr + rem;
            f16x8 a  = *(const f16x8*)(sfcH + (tr * 16 + row) * 40 + kg * 8);
            f16x8 bf = *(const f16x8*)(sfcH + (tc * 16 + row) * 40 + kg * 8);
            f32x4 acc = __builtin_amdgcn_mfma_f32_16x16x32_f16(a, bf, splat4(0.f), 0, 0, 0);
            const int c = tc * 16 + row;
            const float nc = (c < NN) ? snrm[c] : 1.f;
            const float wgt = (tr == tc) ? 1.f : 2.f;
            const bool mirror = (tr != tc);
            #pragma unroll
            for (int i = 0; i < 4; ++i) {
                const int r = tr * 16 + kg * 4 + i;
                float dist = 0.f;
                if (r < NN && c < NN && r != c)
                    dist = 1.f - acc[i] * __frcp_rn(snrm[r] * nc);
                psum += wgt * dist;
                sLh[r * 136 + c] = (_Float16)dist;
                if (mirror) sLh[c * 136 + r] = (_Float16)dist;
            }
        }
        #pragma unroll
        for (int d = 1; d < 64; d <<= 1) psum += __shfl_xor(psum, d);
        if (lane == 0) red[wave] = psum;
    }
    __syncthreads();

    // ---- P3 ----
    {
        const float sg = (red[0] + red[1] + red[2] + red[3]) * (1.f / (float)(NN * NN));
        const float inv2s2 = 1.f / (2.f * sg * sg);
        if (tid < 228) {
            const int r = tid >> 1, half = tid & 1;
            const float idxr = sidx[r];
            float rsum = 0.f;
            _Float16* rp = sLh + r * 136 + half * 57;
            const int c0 = half * 57;
            for (int j = 0; j < 57; ++j) {
                float d = (float)rp[j];
                float A = idxr * sidx[c0 + j] * __expf(-d * d * inv2s2);
                rsum += A;
                rp[j] = (_Float16)A;
            }
            rsum += __shfl_xor(rsum, 1);
            if (half == 0) {
                float dv = rsqrtf(rsum);
                if (isinf(dv)) dv = 0.f;
                sdv[r] = dv;
            }
        }
    }
    __syncthreads();

    // ---- P4 ----
    {
        unsigned int* L32 = (unsigned int*)sLh;
        for (int e2 = tid; e2 < NN * 57; e2 += 256) {
            const int r = e2 / 57, cp = e2 - r * 57;
            const unsigned int u = L32[r * 68 + cp];
            union { unsigned int uu; _Float16 h[2]; } in;
            in.uu = u;
            const float dr = sdv[r];
            float v0 = (float)in.h[0] * dr * sdv[2 * cp];
            float v1 = (float)in.h[1] * dr * sdv[2 * cp + 1];
            L32[r * 68 + cp] = pk2h(v0, v1);
        }
        for (int e = tid; e < NN * C2; e += 256) {
            const int n = e / C2, o = e - n * C2;
            float acc = 0.f;
            #pragma unroll
            for (int d = 0; d < C3; ++d) acc = fmaf(sfe[n * C3 + d], sg1[d * C2 + o], acc);
            t1h[o * 136 + n] = (_Float16)(acc * sidx[n] + sg1b[o]);
        }
    }
    __syncthreads();

    // ---- P5 ----
    {
        const int row = lane & 15;
        const int kg  = lane >> 4;
        #pragma unroll
        for (int tt = 0; tt < 2; ++tt) {
            const int tr = wave * 2 + tt;
            f32x4 acc = splat4(0.f);
            #pragma unroll
            for (int ks = 0; ks < 4; ++ks) {
                f16x8 a = *(const f16x8*)(sLh + (tr * 16 + row) * 136 + ks * 32 + kg * 8);
                f16x8 bf = *(const f16x8*)(t1h + row * 136 + ks * 32 + kg * 8);
                acc = __builtin_amdgcn_mfma_f32_16x16x32_f16(a, bf, acc, 0, 0, 0);
            }
            #pragma unroll
            for (int i = 0; i < 4; ++i) {
                const int n = tr * 16 + kg * 4 + i;
                h1f[n * 16 + row] = elu_f(acc[i]);
            }
        }
    }
    __syncthreads();

    // ---- P6 ----
    for (int e = tid; e < NN * C1; e += 256) {
        const int n = e / C1, c = e - n * C1;
        float acc = sg2b[c];
        #pragma unroll
        for (int o = 0; o < C2; ++o) acc = fmaf(h1f[n * 16 + o], sg2[o * C1 + c], acc);
        t1h[c * 136 + n] = (_Float16)acc;
    }
    __syncthreads();

    // ---- P7 ----
    {
        const int row = lane & 15;
        const int kg  = lane >> 4;
        #pragma unroll
        for (int tt = 0; tt < 2; ++tt) {
            const int tr = wave * 2 + tt;
            f32x4 acc = splat4(0.f);
            #pragma unroll
            for (int ks = 0; ks < 4; ++ks) {
                f16x8 a = *(const f16x8*)(sLh + (tr * 16 + row) * 136 + ks * 32 + kg * 8);
                f16x8 bf = *(const f16x8*)(t1h + row * 136 + ks * 32 + kg * 8);
                acc = __builtin_amdgcn_mfma_f32_16x16x32_f16(a, bf, acc, 0, 0, 0);
            }
            if (row < C1) {
                #pragma unroll
                for (int i = 0; i < 4; ++i) {
                    const int n = tr * 16 + kg * 4 + i;
                    h2T[row * 132 + n] = elu_f(acc[i]);
                }
            }
        }
    }
    __syncthreads();

    // ---- P8 ----
    if (tid < 160) {
        const int c = tid >> 5, s = tid & 31;
        float pmax = -INFINITY, rmin = INFINITY, sum = 0.f;
        #pragma unroll
        for (int k = 0; k < 4; ++k) {
            const int n = s + 32 * k;
            if (n < NN) {
                float v = h2T[c * 132 + n];
                pmax = fmaxf(pmax, v);
                rmin = fminf(rmin, 1.f / v);
                sum += v;
            }
        }
        #pragma unroll
        for (int d = 16; d > 0; d >>= 1) {
            pmax = fmaxf(pmax, __shfl_xor(pmax, d));
            rmin = fminf(rmin, __shfl_xor(rmin, d));
            sum += __shfl_xor(sum, d);
        }
        if (s == 0) {
            float nmax = 1.f / rmin;
            sfeat[c] = (pmax == 0.f) ? nmax : pmax;
            sfeat[C1 + c] = sum;
        }
    }
    __syncthreads();

    if (tid == 0) {
        float l0 = sdb[0], l1 = sdb[1];
        #pragma unroll
        for (int j = 0; j < 10; ++j) {
            l0 += sfeat[j] * sdw[j * 2 + 0];
            l1 += sfeat[j] * sdw[j * 2 + 1];
        }
        float mx = fmaxf(l0, l1);
        float e0 = expf(l0 - mx), e1 = expf(l1 - mx);
        float s = e0 + e1;
        out[b * 2 + 0] = e0 / s;
        out[b * 2 + 1] = e1 / s;
    }
}

extern "C" void kernel_launch(void* const* d_in, const int* in_sizes, int n_in,
                              void* d_out, int out_size, void* d_ws, size_t ws_size,
                              hipStream_t stream) {
    const float* x       = (const float*)d_in[0];
    const float* conv1_w = (const float*)d_in[1];
    const float* conv1_b = (const float*)d_in[2];
    const float* ln1_g   = (const float*)d_in[3];
    const float* ln1_b   = (const float*)d_in[4];
    const float* conv2_w = (const float*)d_in[5];
    const float* conv2_b = (const float*)d_in[6];
    const float* ln2_g   = (const float*)d_in[7];
    const float* ln2_b   = (const float*)d_in[8];
    const float* conv3_w = (const float*)d_in[9];
    const float* conv3_b = (const float*)d_in[10];
    const float* ln3_g   = (const float*)d_in[11];
    const float* ln3_b   = (const float*)d_in[12];
    const float* agent_w = (const float*)d_in[13];
    const float* agent_b = (const float*)d_in[14];
    const float* gconv1_w= (const float*)d_in[15];
    const float* gconv1_b= (const float*)d_in[16];
    const float* gconv2_w= (const float*)d_in[17];
    const float* gconv2_b= (const float*)d_in[18];
    const float* dense_w = (const float*)d_in[19];
    const float* dense_b = (const float*)d_in[20];
    const int*   rl      = (const int*)d_in[21];
    float* out = (float*)d_out;

    const int B = in_sizes[0] / (NH * WIN);
    const int nrows = B * NH;
    _Float16* wbuf = (_Float16*)d_ws;
    float* feats = (float*)((char*)d_ws + FEATS_OFF);

    dim3 block(256);
    hipLaunchKernelGGL(prep_kernel, dim3(32), block, 0, stream,
                       conv1_w, conv2_w, conv3_w, wbuf);

    dim3 grid1((nrows + RPB - 1) / RPB);
    hipLaunchKernelGGL(conv_rows_kernel, grid1, block, 0, stream,
                       x, (const _Float16*)wbuf,
                       conv1_b, ln1_g, ln1_b,
                       conv2_b, ln2_g, ln2_b,
                       conv3_b, ln3_g, ln3_b,
                       feats, nrows);

    dim3 grid2(B);
    hipLaunchKernelGGL(graph_kernel, grid2, block, 0, stream,
                       feats, agent_w, agent_b,
                       gconv1_w, gconv1_b, gconv2_w, gconv2_b,
                       dense_w, dense_b, rl, out);
}